// Round 3
// baseline (898.360 us; speedup 1.0000x reference)
//
#include <hip/hip_runtime.h>
#include <hip/hip_bf16.h>
#include <math.h>

#define D 128
#define AGG_THREADS 128
#define CHUNK 512
#define BSHIFT 8                 // 256 dst nodes per bucket
#define BUCKET_CAP 5120          // mean load 4096, sigma ~64 -> 16 sigma margin
#define OFL_CAP 8192

// ---------- helpers ----------
__device__ __forceinline__ unsigned short f2bf(float f) {
    union { float f; unsigned int u; } c; c.f = f;
    unsigned int u = c.u;
    unsigned int r = (u + 0x7FFFu + ((u >> 16) & 1u)) >> 16;  // RNE
    return (unsigned short)r;
}
__device__ __forceinline__ void unpack2(unsigned int w, float& lo, float& hi) {
    union { unsigned int u; float f; } c;
    c.u = w << 16;          lo = c.f;
    c.u = w & 0xFFFF0000u;  hi = c.f;
}

// ---------- prep: el/er dots + bf16 copy of feat_src ----------
__global__ void prep_kernel(const float* __restrict__ feat_src,
                            const float* __restrict__ feat_dst,
                            const float* __restrict__ attn_l,
                            const float* __restrict__ attn_r,
                            float* __restrict__ el, float* __restrict__ er,
                            unsigned short* __restrict__ feat_bf, int store_bf,
                            int Ns, int Nd) {
    int wave = threadIdx.x >> 6;
    int lane = threadIdx.x & 63;
    int node = blockIdx.x * 4 + wave;
    if (node >= Ns + Nd) return;
    bool is_src = node < Ns;
    const float* feat = is_src ? feat_src + (size_t)node * D
                               : feat_dst + (size_t)(node - Ns) * D;
    const float* attn = is_src ? attn_l : attn_r;
    float2 a = ((const float2*)attn)[lane];
    float2 v = ((const float2*)feat)[lane];
    if (is_src && store_bf) {
        ushort2 h; h.x = f2bf(v.x); h.y = f2bf(v.y);
        ((ushort2*)(feat_bf + (size_t)node * D))[lane] = h;
    }
    float s = v.x * a.x + v.y * a.y;
    #pragma unroll
    for (int off = 32; off > 0; off >>= 1)
        s += __shfl_down(s, off, 64);
    if (lane == 0) {
        if (is_src) el[node] = s;
        else        er[node - Ns] = s;
    }
}

// ---------- pass A: histogram + partition edges into dst-range buckets ----------
__global__ void bin_kernel(const int* __restrict__ src, const int* __restrict__ dst, int E,
                           int* __restrict__ counts,
                           uint2* __restrict__ bins, int* __restrict__ bcur,
                           uint2* __restrict__ ofl, int* __restrict__ ofl_cnt) {
    int stride = gridDim.x * blockDim.x;
    for (int k = blockIdx.x * blockDim.x + threadIdx.x; k < E; k += stride) {
        int s = src[k], j = dst[k];
        atomicAdd(&counts[j], 1);                 // fire-and-forget histogram
        int b = j >> BSHIFT;
        int r = atomicAdd(&bcur[b], 1);
        if (r < BUCKET_CAP) {
            bins[(size_t)b * BUCKET_CAP + r] = make_uint2((unsigned)s, (unsigned)j);
        } else {
            int o = atomicAdd(ofl_cnt, 1);
            if (o < OFL_CAP) ofl[o] = make_uint2((unsigned)s, (unsigned)j);
        }
    }
}

// ---------- 3-kernel exclusive scan ----------
__global__ void scan1_kernel(const int* __restrict__ counts, int* __restrict__ offsets,
                             int* __restrict__ blockSums, int N) {
    __shared__ int tile[256];
    int tid = threadIdx.x;
    int i = blockIdx.x * 256 + tid;
    int v = (i < N) ? counts[i] : 0;
    tile[tid] = v;
    __syncthreads();
    for (int off = 1; off < 256; off <<= 1) {
        int t = (tid >= off) ? tile[tid - off] : 0;
        __syncthreads();
        tile[tid] += t;
        __syncthreads();
    }
    int incl = tile[tid];
    if (i < N) offsets[i] = incl - v;
    if (tid == 255) blockSums[blockIdx.x] = incl;
}

__global__ void scan2_kernel(int* __restrict__ bs, int nb) {
    __shared__ int tile[256];
    int tid = threadIdx.x;
    int carry = 0;
    for (int base = 0; base < nb; base += 256) {
        int i = base + tid;
        int v = (i < nb) ? bs[i] : 0;
        __syncthreads();
        tile[tid] = v;
        __syncthreads();
        for (int off = 1; off < 256; off <<= 1) {
            int t = (tid >= off) ? tile[tid - off] : 0;
            __syncthreads();
            tile[tid] += t;
            __syncthreads();
        }
        int incl = tile[tid];
        if (i < nb) bs[i] = incl - v + carry;
        carry += tile[255];
    }
}

__global__ void scan3_kernel(int* __restrict__ offsets, const int* __restrict__ blockSums, int N) {
    int i = blockIdx.x * 256 + threadIdx.x;
    if (i < N) offsets[i] += blockSums[blockIdx.x];
}

// ---------- drain overflow edges (normally zero work) ----------
__global__ void drain_kernel(const uint2* __restrict__ ofl, const int* __restrict__ ofl_cnt,
                             const int* __restrict__ offsets,
                             int* __restrict__ gcursor, int* __restrict__ perm_src) {
    int n = min(*ofl_cnt, OFL_CAP);
    int stride = gridDim.x * blockDim.x;
    for (int k = blockIdx.x * blockDim.x + threadIdx.x; k < n; k += stride) {
        uint2 e = ofl[k];
        int j = (int)e.y;
        int p = offsets[j] + atomicAdd(&gcursor[j], 1);
        perm_src[p] = (int)e.x;
    }
}

// ---------- pass B: per-bucket LDS-ranked scatter into CSR ----------
// One 256-thread block per bucket; writes land in a contiguous ~16 KB perm region.
__global__ void scatter_kernel(const uint2* __restrict__ bins, const int* __restrict__ bcur,
                               const int* __restrict__ offsets,
                               const int* __restrict__ gcursor,
                               int* __restrict__ perm_src, int Nd) {
    __shared__ int lcur[1 << BSHIFT];
    int b = blockIdx.x;
    int base = b << BSHIFT;
    int tid = threadIdx.x;
    if (base + tid < Nd) lcur[tid] = gcursor[base + tid];  // start after overflow ranks
    __syncthreads();
    int n = min(bcur[b], BUCKET_CAP);
    const uint2* mybin = bins + (size_t)b * BUCKET_CAP;
    for (int t = tid; t < n; t += 256) {
        uint2 e = mybin[t];
        int j = (int)e.y;
        int rank = atomicAdd(&lcur[j - base], 1);
        perm_src[offsets[j] + rank] = (int)e.x;
    }
}

// ---------- fallback: histogram + atomic fill (R1 path) ----------
__global__ void hist_kernel(const int* __restrict__ dst, int E, int* __restrict__ counts) {
    int stride = gridDim.x * blockDim.x;
    for (int k = blockIdx.x * blockDim.x + threadIdx.x; k < E; k += stride)
        atomicAdd(&counts[dst[k]], 1);
}
__global__ void fill_kernel(const int* __restrict__ src, const int* __restrict__ dst, int E,
                            const int* __restrict__ offsets, int* __restrict__ cursor,
                            int* __restrict__ perm_src) {
    int stride = gridDim.x * blockDim.x;
    for (int k = blockIdx.x * blockDim.x + threadIdx.x; k < E; k += stride) {
        int j = dst[k];
        int p = offsets[j] + atomicAdd(&cursor[j], 1);
        perm_src[p] = src[k];
    }
}

// ---------- block reductions (128 threads = 2 waves) ----------
__device__ __forceinline__ float block_max128(float v, float* red, int tid) {
    #pragma unroll
    for (int off = 32; off > 0; off >>= 1)
        v = fmaxf(v, __shfl_down(v, off, 64));
    __syncthreads();
    if ((tid & 63) == 0) red[tid >> 6] = v;
    __syncthreads();
    return fmaxf(red[0], red[1]);
}
__device__ __forceinline__ float block_sum128(float v, float* red, int tid) {
    #pragma unroll
    for (int off = 32; off > 0; off >>= 1)
        v += __shfl_down(v, off, 64);
    __syncthreads();
    if ((tid & 63) == 0) red[tid >> 6] = v;
    __syncthreads();
    return red[0] + red[1];
}

// ---------- bf16-vectorized aggregate ----------
__global__ void gat_aggregate_bf16_kernel(const unsigned short* __restrict__ feat_bf,
                                          const float* __restrict__ el,
                                          const float* __restrict__ er,
                                          const int* __restrict__ offsets,
                                          const int* __restrict__ counts,
                                          const int* __restrict__ perm_src,
                                          float* __restrict__ out, int Nd) {
    __shared__ float w_sh[CHUNK];
    __shared__ int   s_sh[CHUNK];
    __shared__ float red[2];
    __shared__ float acc_sh[8][D];

    int j = blockIdx.x;
    int tid = threadIdx.x;
    int cnt = counts[j];
    size_t orow = (size_t)j * D;
    if (cnt == 0) { out[orow + tid] = 0.0f; return; }

    int beg = offsets[j];
    float erj = er[j];
    int g = tid >> 4, u = tid & 15;
    float acc[8];
    #pragma unroll
    for (int k = 0; k < 8; ++k) acc[k] = 0.0f;
    float inv;
    const unsigned short* fb = feat_bf + (size_t)u * 8;

    if (cnt <= CHUNK) {
        float lmax = -INFINITY;
        for (int t = tid; t < cnt; t += AGG_THREADS) {
            int s = perm_src[beg + t];
            float e = el[s] + erj;
            e = (e >= 0.0f) ? e : 0.01f * e;  // leaky_relu
            s_sh[t] = s;
            w_sh[t] = e;
            lmax = fmaxf(lmax, e);
        }
        float m = block_max128(lmax, red, tid);
        float lsum = 0.0f;
        for (int t = tid; t < cnt; t += AGG_THREADS) {
            float a = __expf(w_sh[t] - m);
            w_sh[t] = a;
            lsum += a;
        }
        float den = block_sum128(lsum, red, tid);
        inv = 1.0f / den;
        __syncthreads();
        for (int t = g; t < cnt; t += 8) {
            int s = s_sh[t];
            float w = w_sh[t];
            uint4 v = *(const uint4*)(fb + (size_t)s * D);
            float f[8];
            unpack2(v.x, f[0], f[1]); unpack2(v.y, f[2], f[3]);
            unpack2(v.z, f[4], f[5]); unpack2(v.w, f[6], f[7]);
            #pragma unroll
            for (int k = 0; k < 8; ++k) acc[k] += w * f[k];
        }
    } else {
        float lmax = -INFINITY;
        for (int t = tid; t < cnt; t += AGG_THREADS) {
            int s = perm_src[beg + t];
            float e = el[s] + erj;
            e = (e >= 0.0f) ? e : 0.01f * e;
            lmax = fmaxf(lmax, e);
        }
        float m = block_max128(lmax, red, tid);
        float lsum = 0.0f;
        for (int t = tid; t < cnt; t += AGG_THREADS) {
            int s = perm_src[beg + t];
            float e = el[s] + erj;
            e = (e >= 0.0f) ? e : 0.01f * e;
            lsum += __expf(e - m);
        }
        float den = block_sum128(lsum, red, tid);
        inv = 1.0f / den;
        for (int base = 0; base < cnt; base += CHUNK) {
            int n = min(CHUNK, cnt - base);
            __syncthreads();
            for (int t = tid; t < n; t += AGG_THREADS) {
                int s = perm_src[beg + base + t];
                float e = el[s] + erj;
                e = (e >= 0.0f) ? e : 0.01f * e;
                s_sh[t] = s;
                w_sh[t] = __expf(e - m);
            }
            __syncthreads();
            for (int t = g; t < n; t += 8) {
                int s = s_sh[t];
                float w = w_sh[t];
                uint4 v = *(const uint4*)(fb + (size_t)s * D);
                float f[8];
                unpack2(v.x, f[0], f[1]); unpack2(v.y, f[2], f[3]);
                unpack2(v.z, f[4], f[5]); unpack2(v.w, f[6], f[7]);
                #pragma unroll
                for (int k = 0; k < 8; ++k) acc[k] += w * f[k];
            }
        }
    }
    #pragma unroll
    for (int k = 0; k < 8; ++k) acc_sh[g][u * 8 + k] = acc[k];
    __syncthreads();
    float r = 0.0f;
    #pragma unroll
    for (int g2 = 0; g2 < 8; ++g2) r += acc_sh[g2][tid];
    out[orow + tid] = r * inv;
}

// ---------- fp32 fallback aggregate ----------
__global__ void gat_aggregate_f32_kernel(const float* __restrict__ feat_src,
                                         const float* __restrict__ el,
                                         const float* __restrict__ er,
                                         const int* __restrict__ offsets,
                                         const int* __restrict__ counts,
                                         const int* __restrict__ perm_src,
                                         float* __restrict__ out, int Nd) {
    __shared__ float w_sh[CHUNK];
    __shared__ int   s_sh[CHUNK];
    __shared__ float red[2];

    int j = blockIdx.x;
    int tid = threadIdx.x;
    int cnt = counts[j];
    size_t orow = (size_t)j * D;
    if (cnt == 0) { out[orow + tid] = 0.0f; return; }

    int beg = offsets[j];
    float erj = er[j];
    float acc = 0.0f;
    float inv;

    if (cnt <= CHUNK) {
        float lmax = -INFINITY;
        for (int t = tid; t < cnt; t += AGG_THREADS) {
            int s = perm_src[beg + t];
            float e = el[s] + erj;
            e = (e >= 0.0f) ? e : 0.01f * e;
            s_sh[t] = s;
            w_sh[t] = e;
            lmax = fmaxf(lmax, e);
        }
        float m = block_max128(lmax, red, tid);
        float lsum = 0.0f;
        for (int t = tid; t < cnt; t += AGG_THREADS) {
            float a = __expf(w_sh[t] - m);
            w_sh[t] = a;
            lsum += a;
        }
        float den = block_sum128(lsum, red, tid);
        inv = 1.0f / den;
        __syncthreads();
        int t = 0;
        for (; t + 4 <= cnt; t += 4) {
            float f0 = feat_src[(size_t)s_sh[t + 0] * D + tid];
            float f1 = feat_src[(size_t)s_sh[t + 1] * D + tid];
            float f2 = feat_src[(size_t)s_sh[t + 2] * D + tid];
            float f3 = feat_src[(size_t)s_sh[t + 3] * D + tid];
            acc += f0 * w_sh[t + 0] + f1 * w_sh[t + 1] + f2 * w_sh[t + 2] + f3 * w_sh[t + 3];
        }
        for (; t < cnt; ++t)
            acc += feat_src[(size_t)s_sh[t] * D + tid] * w_sh[t];
    } else {
        float lmax = -INFINITY;
        for (int t = tid; t < cnt; t += AGG_THREADS) {
            int s = perm_src[beg + t];
            float e = el[s] + erj;
            e = (e >= 0.0f) ? e : 0.01f * e;
            lmax = fmaxf(lmax, e);
        }
        float m = block_max128(lmax, red, tid);
        float lsum = 0.0f;
        for (int t = tid; t < cnt; t += AGG_THREADS) {
            int s = perm_src[beg + t];
            float e = el[s] + erj;
            e = (e >= 0.0f) ? e : 0.01f * e;
            lsum += __expf(e - m);
        }
        float den = block_sum128(lsum, red, tid);
        inv = 1.0f / den;
        for (int base = 0; base < cnt; base += CHUNK) {
            int n = min(CHUNK, cnt - base);
            __syncthreads();
            for (int t = tid; t < n; t += AGG_THREADS) {
                int s = perm_src[beg + base + t];
                float e = el[s] + erj;
                e = (e >= 0.0f) ? e : 0.01f * e;
                s_sh[t] = s;
                w_sh[t] = __expf(e - m);
            }
            __syncthreads();
            for (int t = 0; t < n; ++t)
                acc += feat_src[(size_t)s_sh[t] * D + tid] * w_sh[t];
        }
    }
    out[orow + tid] = acc * inv;
}

extern "C" void kernel_launch(void* const* d_in, const int* in_sizes, int n_in,
                              void* d_out, int out_size, void* d_ws, size_t ws_size,
                              hipStream_t stream) {
    const float* feat_src = (const float*)d_in[0];
    const float* feat_dst = (const float*)d_in[1];
    const int*   src      = (const int*)d_in[2];
    const int*   dst      = (const int*)d_in[3];
    const float* attn_l   = (const float*)d_in[4];
    const float* attn_r   = (const float*)d_in[5];
    float* out = (float*)d_out;

    int Ns = in_sizes[0] / D;
    int Nd = in_sizes[1] / D;
    int E  = in_sizes[2];
    int nb = (Nd + 255) / 256;      // scan blocks == number of buckets (BSHIFT=8)
    int NB = (Nd + (1 << BSHIFT) - 1) >> BSHIFT;

    // workspace carve (256B aligned); zero-init region is contiguous: counts..ofl_cnt
    char* p = (char*)d_ws;
    auto carve = [&](size_t bytes) { void* r = (void*)p; p += (bytes + 255) & ~(size_t)255; return r; };
    float* el        = (float*)carve((size_t)Ns * 4);
    float* er        = (float*)carve((size_t)Nd * 4);
    int*   counts    = (int*)carve((size_t)Nd * 4);
    int*   gcursor   = (int*)carve((size_t)Nd * 4);
    int*   bcur      = (int*)carve((size_t)NB * 4);
    int*   ofl_cnt   = (int*)carve(4);
    char*  zero_end  = p;
    int*   offsets   = (int*)carve((size_t)Nd * 4);
    int*   blockSums = (int*)carve((size_t)nb * 4);
    int*   perm_src  = (int*)carve((size_t)E * 4);
    uint2* ofl       = (uint2*)carve((size_t)OFL_CAP * 8);

    size_t used = (size_t)(p - (char*)d_ws);
    size_t bins_bytes = (size_t)NB * BUCKET_CAP * 8;
    int use_bins = (used + bins_bytes + 256 <= ws_size) ? 1 : 0;
    uint2* bins = use_bins ? (uint2*)carve(bins_bytes) : nullptr;

    used = (size_t)(p - (char*)d_ws);
    size_t bf_bytes = (size_t)Ns * D * 2;
    int use_bf16 = (used + bf_bytes + 256 <= ws_size) ? 1 : 0;
    unsigned short* feat_bf = use_bf16 ? (unsigned short*)carve(bf_bytes) : nullptr;

    hipMemsetAsync(counts, 0, (size_t)(zero_end - (char*)counts), stream);

    int total = Ns + Nd;
    prep_kernel<<<(total + 3) / 4, 256, 0, stream>>>(feat_src, feat_dst, attn_l, attn_r,
                                                     el, er, feat_bf, use_bf16, Ns, Nd);
    if (use_bins) {
        bin_kernel<<<2048, 256, 0, stream>>>(src, dst, E, counts, bins, bcur, ofl, ofl_cnt);
    } else {
        hist_kernel<<<2048, 256, 0, stream>>>(dst, E, counts);
    }
    scan1_kernel<<<nb, 256, 0, stream>>>(counts, offsets, blockSums, Nd);
    scan2_kernel<<<1, 256, 0, stream>>>(blockSums, nb);
    scan3_kernel<<<nb, 256, 0, stream>>>(offsets, blockSums, Nd);
    if (use_bins) {
        drain_kernel<<<32, 256, 0, stream>>>(ofl, ofl_cnt, offsets, gcursor, perm_src);
        scatter_kernel<<<NB, 256, 0, stream>>>(bins, bcur, offsets, gcursor, perm_src, Nd);
    } else {
        fill_kernel<<<2048, 256, 0, stream>>>(src, dst, E, offsets, gcursor, perm_src);
    }
    if (use_bf16) {
        gat_aggregate_bf16_kernel<<<Nd, AGG_THREADS, 0, stream>>>(feat_bf, el, er, offsets,
                                                                  counts, perm_src, out, Nd);
    } else {
        gat_aggregate_f32_kernel<<<Nd, AGG_THREADS, 0, stream>>>(feat_src, el, er, offsets,
                                                                 counts, perm_src, out, Nd);
    }
}

// Round 4
// 368.548 us; speedup vs baseline: 2.4376x; 2.4376x over previous
//
#include <hip/hip_runtime.h>
#include <hip/hip_bf16.h>
#include <math.h>

#define D 128
#define AGG_THREADS 128
#define CHUNK 512
#define BSHIFT 8                 // 256 dst nodes per bucket
#define BUCKET_CAP 5120          // mean load 4096, sigma ~64 -> 16 sigma margin
#define OFL_CAP 8192
#define MAXB 1024                // max buckets supported by partition_kernel LDS
#define PART_WGS 256             // workgroups in partition pass

// ---------- helpers ----------
__device__ __forceinline__ unsigned short f2bf(float f) {
    union { float f; unsigned int u; } c; c.f = f;
    unsigned int u = c.u;
    unsigned int r = (u + 0x7FFFu + ((u >> 16) & 1u)) >> 16;  // RNE
    return (unsigned short)r;
}
__device__ __forceinline__ void unpack2(unsigned int w, float& lo, float& hi) {
    union { unsigned int u; float f; } c;
    c.u = w << 16;          lo = c.f;
    c.u = w & 0xFFFF0000u;  hi = c.f;
}

// ---------- prep: el/er dots + bf16 copy of feat_src ----------
__global__ void prep_kernel(const float* __restrict__ feat_src,
                            const float* __restrict__ feat_dst,
                            const float* __restrict__ attn_l,
                            const float* __restrict__ attn_r,
                            float* __restrict__ el, float* __restrict__ er,
                            unsigned short* __restrict__ feat_bf, int store_bf,
                            int Ns, int Nd) {
    int wave = threadIdx.x >> 6;
    int lane = threadIdx.x & 63;
    int node = blockIdx.x * 4 + wave;
    if (node >= Ns + Nd) return;
    bool is_src = node < Ns;
    const float* feat = is_src ? feat_src + (size_t)node * D
                               : feat_dst + (size_t)(node - Ns) * D;
    const float* attn = is_src ? attn_l : attn_r;
    float2 a = ((const float2*)attn)[lane];
    float2 v = ((const float2*)feat)[lane];
    if (is_src && store_bf) {
        ushort2 h; h.x = f2bf(v.x); h.y = f2bf(v.y);
        ((ushort2*)(feat_bf + (size_t)node * D))[lane] = h;
    }
    float s = v.x * a.x + v.y * a.y;
    #pragma unroll
    for (int off = 32; off > 0; off >>= 1)
        s += __shfl_down(s, off, 64);
    if (lane == 0) {
        if (is_src) el[node] = s;
        else        er[node - Ns] = s;
    }
}

// ---------- pass A: per-WG counting-sort partition into dst-range buckets ----------
// Each WG owns a contiguous edge chunk: LDS bucket histogram -> ONE global
// reservation atomic per (WG, bucket) -> LDS-ranked write into its private run.
// Runs are contiguous (~16 edges = 128 B) so L2 merges the lines.
__global__ void partition_kernel(const int* __restrict__ src, const int* __restrict__ dst,
                                 int E, int chunk, int nbk,
                                 int* __restrict__ counts,
                                 uint2* __restrict__ bins, int* __restrict__ bcur,
                                 uint2* __restrict__ ofl, int* __restrict__ ofl_cnt) {
    __shared__ int hist[MAXB];
    __shared__ int lbase[MAXB];
    int tid = threadIdx.x;
    int e0 = blockIdx.x * chunk;
    int e1 = min(E, e0 + chunk);
    if (e0 >= E) return;

    for (int i = tid; i < nbk; i += 256) hist[i] = 0;
    __syncthreads();

    // pass 1: per-dst counts (fire-and-forget) + LDS bucket histogram
    for (int k = e0 + tid; k < e1; k += 256) {
        int j = dst[k];
        atomicAdd(&counts[j], 1);
        atomicAdd(&hist[j >> BSHIFT], 1);
    }
    __syncthreads();

    // reserve one run per non-empty bucket
    for (int i = tid; i < nbk; i += 256) {
        int h = hist[i];
        lbase[i] = h ? atomicAdd(&bcur[i], h) : 0;
        hist[i] = 0;                       // reuse as local cursor
    }
    __syncthreads();

    // pass 2: rank via LDS atomics, write into reserved run
    for (int k = e0 + tid; k < e1; k += 256) {
        int s = src[k], j = dst[k];
        int b = j >> BSHIFT;
        int r = lbase[b] + atomicAdd(&hist[b], 1);
        if (r < BUCKET_CAP) {
            bins[(size_t)b * BUCKET_CAP + r] = make_uint2((unsigned)s, (unsigned)j);
        } else {
            int o = atomicAdd(ofl_cnt, 1);
            if (o < OFL_CAP) ofl[o] = make_uint2((unsigned)s, (unsigned)j);
        }
    }
}

// ---------- 3-kernel exclusive scan ----------
__global__ void scan1_kernel(const int* __restrict__ counts, int* __restrict__ offsets,
                             int* __restrict__ blockSums, int N) {
    __shared__ int tile[256];
    int tid = threadIdx.x;
    int i = blockIdx.x * 256 + tid;
    int v = (i < N) ? counts[i] : 0;
    tile[tid] = v;
    __syncthreads();
    for (int off = 1; off < 256; off <<= 1) {
        int t = (tid >= off) ? tile[tid - off] : 0;
        __syncthreads();
        tile[tid] += t;
        __syncthreads();
    }
    int incl = tile[tid];
    if (i < N) offsets[i] = incl - v;
    if (tid == 255) blockSums[blockIdx.x] = incl;
}

__global__ void scan2_kernel(int* __restrict__ bs, int nb) {
    __shared__ int tile[256];
    int tid = threadIdx.x;
    int carry = 0;
    for (int base = 0; base < nb; base += 256) {
        int i = base + tid;
        int v = (i < nb) ? bs[i] : 0;
        __syncthreads();
        tile[tid] = v;
        __syncthreads();
        for (int off = 1; off < 256; off <<= 1) {
            int t = (tid >= off) ? tile[tid - off] : 0;
            __syncthreads();
            tile[tid] += t;
            __syncthreads();
        }
        int incl = tile[tid];
        if (i < nb) bs[i] = incl - v + carry;
        carry += tile[255];
    }
}

__global__ void scan3_kernel(int* __restrict__ offsets, const int* __restrict__ blockSums, int N) {
    int i = blockIdx.x * 256 + threadIdx.x;
    if (i < N) offsets[i] += blockSums[blockIdx.x];
}

// ---------- drain overflow edges (normally zero work) ----------
__global__ void drain_kernel(const uint2* __restrict__ ofl, const int* __restrict__ ofl_cnt,
                             const int* __restrict__ offsets,
                             int* __restrict__ gcursor, int* __restrict__ perm_src) {
    int n = min(*ofl_cnt, OFL_CAP);
    int stride = gridDim.x * blockDim.x;
    for (int k = blockIdx.x * blockDim.x + threadIdx.x; k < n; k += stride) {
        uint2 e = ofl[k];
        int j = (int)e.y;
        int p = offsets[j] + atomicAdd(&gcursor[j], 1);
        perm_src[p] = (int)e.x;
    }
}

// ---------- pass B: per-bucket LDS-ranked scatter into CSR ----------
__global__ void scatter_kernel(const uint2* __restrict__ bins, const int* __restrict__ bcur,
                               const int* __restrict__ offsets,
                               const int* __restrict__ gcursor,
                               int* __restrict__ perm_src, int Nd) {
    __shared__ int lcur[1 << BSHIFT];
    int b = blockIdx.x;
    int base = b << BSHIFT;
    int tid = threadIdx.x;
    if (base + tid < Nd) lcur[tid] = gcursor[base + tid];  // start after overflow ranks
    __syncthreads();
    int n = min(bcur[b], BUCKET_CAP);
    const uint2* mybin = bins + (size_t)b * BUCKET_CAP;
    for (int t = tid; t < n; t += 256) {
        uint2 e = mybin[t];
        int j = (int)e.y;
        int rank = atomicAdd(&lcur[j - base], 1);
        perm_src[offsets[j] + rank] = (int)e.x;
    }
}

// ---------- fallback: histogram + atomic fill (R1/R2 path) ----------
__global__ void hist_kernel(const int* __restrict__ dst, int E, int* __restrict__ counts) {
    int stride = gridDim.x * blockDim.x;
    for (int k = blockIdx.x * blockDim.x + threadIdx.x; k < E; k += stride)
        atomicAdd(&counts[dst[k]], 1);
}
__global__ void fill_kernel(const int* __restrict__ src, const int* __restrict__ dst, int E,
                            const int* __restrict__ offsets, int* __restrict__ cursor,
                            int* __restrict__ perm_src) {
    int stride = gridDim.x * blockDim.x;
    for (int k = blockIdx.x * blockDim.x + threadIdx.x; k < E; k += stride) {
        int j = dst[k];
        int p = offsets[j] + atomicAdd(&cursor[j], 1);
        perm_src[p] = src[k];
    }
}

// ---------- block reductions (128 threads = 2 waves) ----------
__device__ __forceinline__ float block_max128(float v, float* red, int tid) {
    #pragma unroll
    for (int off = 32; off > 0; off >>= 1)
        v = fmaxf(v, __shfl_down(v, off, 64));
    __syncthreads();
    if ((tid & 63) == 0) red[tid >> 6] = v;
    __syncthreads();
    return fmaxf(red[0], red[1]);
}
__device__ __forceinline__ float block_sum128(float v, float* red, int tid) {
    #pragma unroll
    for (int off = 32; off > 0; off >>= 1)
        v += __shfl_down(v, off, 64);
    __syncthreads();
    if ((tid & 63) == 0) red[tid >> 6] = v;
    __syncthreads();
    return red[0] + red[1];
}

// ---------- bf16-vectorized aggregate ----------
__global__ void gat_aggregate_bf16_kernel(const unsigned short* __restrict__ feat_bf,
                                          const float* __restrict__ el,
                                          const float* __restrict__ er,
                                          const int* __restrict__ offsets,
                                          const int* __restrict__ counts,
                                          const int* __restrict__ perm_src,
                                          float* __restrict__ out, int Nd) {
    __shared__ float w_sh[CHUNK];
    __shared__ int   s_sh[CHUNK];
    __shared__ float red[2];
    __shared__ float acc_sh[8][D];

    int j = blockIdx.x;
    int tid = threadIdx.x;
    int cnt = counts[j];
    size_t orow = (size_t)j * D;
    if (cnt == 0) { out[orow + tid] = 0.0f; return; }

    int beg = offsets[j];
    float erj = er[j];
    int g = tid >> 4, u = tid & 15;
    float acc[8];
    #pragma unroll
    for (int k = 0; k < 8; ++k) acc[k] = 0.0f;
    float inv;
    const unsigned short* fb = feat_bf + (size_t)u * 8;

    if (cnt <= CHUNK) {
        float lmax = -INFINITY;
        for (int t = tid; t < cnt; t += AGG_THREADS) {
            int s = perm_src[beg + t];
            float e = el[s] + erj;
            e = (e >= 0.0f) ? e : 0.01f * e;  // leaky_relu
            s_sh[t] = s;
            w_sh[t] = e;
            lmax = fmaxf(lmax, e);
        }
        float m = block_max128(lmax, red, tid);
        float lsum = 0.0f;
        for (int t = tid; t < cnt; t += AGG_THREADS) {
            float a = __expf(w_sh[t] - m);
            w_sh[t] = a;
            lsum += a;
        }
        float den = block_sum128(lsum, red, tid);
        inv = 1.0f / den;
        __syncthreads();
        for (int t = g; t < cnt; t += 8) {
            int s = s_sh[t];
            float w = w_sh[t];
            uint4 v = *(const uint4*)(fb + (size_t)s * D);
            float f[8];
            unpack2(v.x, f[0], f[1]); unpack2(v.y, f[2], f[3]);
            unpack2(v.z, f[4], f[5]); unpack2(v.w, f[6], f[7]);
            #pragma unroll
            for (int k = 0; k < 8; ++k) acc[k] += w * f[k];
        }
    } else {
        float lmax = -INFINITY;
        for (int t = tid; t < cnt; t += AGG_THREADS) {
            int s = perm_src[beg + t];
            float e = el[s] + erj;
            e = (e >= 0.0f) ? e : 0.01f * e;
            lmax = fmaxf(lmax, e);
        }
        float m = block_max128(lmax, red, tid);
        float lsum = 0.0f;
        for (int t = tid; t < cnt; t += AGG_THREADS) {
            int s = perm_src[beg + t];
            float e = el[s] + erj;
            e = (e >= 0.0f) ? e : 0.01f * e;
            lsum += __expf(e - m);
        }
        float den = block_sum128(lsum, red, tid);
        inv = 1.0f / den;
        for (int base = 0; base < cnt; base += CHUNK) {
            int n = min(CHUNK, cnt - base);
            __syncthreads();
            for (int t = tid; t < n; t += AGG_THREADS) {
                int s = perm_src[beg + base + t];
                float e = el[s] + erj;
                e = (e >= 0.0f) ? e : 0.01f * e;
                s_sh[t] = s;
                w_sh[t] = __expf(e - m);
            }
            __syncthreads();
            for (int t = g; t < n; t += 8) {
                int s = s_sh[t];
                float w = w_sh[t];
                uint4 v = *(const uint4*)(fb + (size_t)s * D);
                float f[8];
                unpack2(v.x, f[0], f[1]); unpack2(v.y, f[2], f[3]);
                unpack2(v.z, f[4], f[5]); unpack2(v.w, f[6], f[7]);
                #pragma unroll
                for (int k = 0; k < 8; ++k) acc[k] += w * f[k];
            }
        }
    }
    #pragma unroll
    for (int k = 0; k < 8; ++k) acc_sh[g][u * 8 + k] = acc[k];
    __syncthreads();
    float r = 0.0f;
    #pragma unroll
    for (int g2 = 0; g2 < 8; ++g2) r += acc_sh[g2][tid];
    out[orow + tid] = r * inv;
}

// ---------- fp32 fallback aggregate ----------
__global__ void gat_aggregate_f32_kernel(const float* __restrict__ feat_src,
                                         const float* __restrict__ el,
                                         const float* __restrict__ er,
                                         const int* __restrict__ offsets,
                                         const int* __restrict__ counts,
                                         const int* __restrict__ perm_src,
                                         float* __restrict__ out, int Nd) {
    __shared__ float w_sh[CHUNK];
    __shared__ int   s_sh[CHUNK];
    __shared__ float red[2];

    int j = blockIdx.x;
    int tid = threadIdx.x;
    int cnt = counts[j];
    size_t orow = (size_t)j * D;
    if (cnt == 0) { out[orow + tid] = 0.0f; return; }

    int beg = offsets[j];
    float erj = er[j];
    float acc = 0.0f;
    float inv;

    if (cnt <= CHUNK) {
        float lmax = -INFINITY;
        for (int t = tid; t < cnt; t += AGG_THREADS) {
            int s = perm_src[beg + t];
            float e = el[s] + erj;
            e = (e >= 0.0f) ? e : 0.01f * e;
            s_sh[t] = s;
            w_sh[t] = e;
            lmax = fmaxf(lmax, e);
        }
        float m = block_max128(lmax, red, tid);
        float lsum = 0.0f;
        for (int t = tid; t < cnt; t += AGG_THREADS) {
            float a = __expf(w_sh[t] - m);
            w_sh[t] = a;
            lsum += a;
        }
        float den = block_sum128(lsum, red, tid);
        inv = 1.0f / den;
        __syncthreads();
        int t = 0;
        for (; t + 4 <= cnt; t += 4) {
            float f0 = feat_src[(size_t)s_sh[t + 0] * D + tid];
            float f1 = feat_src[(size_t)s_sh[t + 1] * D + tid];
            float f2 = feat_src[(size_t)s_sh[t + 2] * D + tid];
            float f3 = feat_src[(size_t)s_sh[t + 3] * D + tid];
            acc += f0 * w_sh[t + 0] + f1 * w_sh[t + 1] + f2 * w_sh[t + 2] + f3 * w_sh[t + 3];
        }
        for (; t < cnt; ++t)
            acc += feat_src[(size_t)s_sh[t] * D + tid] * w_sh[t];
    } else {
        float lmax = -INFINITY;
        for (int t = tid; t < cnt; t += AGG_THREADS) {
            int s = perm_src[beg + t];
            float e = el[s] + erj;
            e = (e >= 0.0f) ? e : 0.01f * e;
            lmax = fmaxf(lmax, e);
        }
        float m = block_max128(lmax, red, tid);
        float lsum = 0.0f;
        for (int t = tid; t < cnt; t += AGG_THREADS) {
            int s = perm_src[beg + t];
            float e = el[s] + erj;
            e = (e >= 0.0f) ? e : 0.01f * e;
            lsum += __expf(e - m);
        }
        float den = block_sum128(lsum, red, tid);
        inv = 1.0f / den;
        for (int base = 0; base < cnt; base += CHUNK) {
            int n = min(CHUNK, cnt - base);
            __syncthreads();
            for (int t = tid; t < n; t += AGG_THREADS) {
                int s = perm_src[beg + base + t];
                float e = el[s] + erj;
                e = (e >= 0.0f) ? e : 0.01f * e;
                s_sh[t] = s;
                w_sh[t] = __expf(e - m);
            }
            __syncthreads();
            for (int t = 0; t < n; ++t)
                acc += feat_src[(size_t)s_sh[t] * D + tid] * w_sh[t];
        }
    }
    out[orow + tid] = acc * inv;
}

extern "C" void kernel_launch(void* const* d_in, const int* in_sizes, int n_in,
                              void* d_out, int out_size, void* d_ws, size_t ws_size,
                              hipStream_t stream) {
    const float* feat_src = (const float*)d_in[0];
    const float* feat_dst = (const float*)d_in[1];
    const int*   src      = (const int*)d_in[2];
    const int*   dst      = (const int*)d_in[3];
    const float* attn_l   = (const float*)d_in[4];
    const float* attn_r   = (const float*)d_in[5];
    float* out = (float*)d_out;

    int Ns = in_sizes[0] / D;
    int Nd = in_sizes[1] / D;
    int E  = in_sizes[2];
    int nb = (Nd + 255) / 256;
    int NB = (Nd + (1 << BSHIFT) - 1) >> BSHIFT;

    // workspace carve (256B aligned); zero-init region is contiguous: counts..ofl_cnt
    char* p = (char*)d_ws;
    auto carve = [&](size_t bytes) { void* r = (void*)p; p += (bytes + 255) & ~(size_t)255; return r; };
    float* el        = (float*)carve((size_t)Ns * 4);
    float* er        = (float*)carve((size_t)Nd * 4);
    int*   counts    = (int*)carve((size_t)Nd * 4);
    int*   gcursor   = (int*)carve((size_t)Nd * 4);
    int*   bcur      = (int*)carve((size_t)NB * 4);
    int*   ofl_cnt   = (int*)carve(4);
    char*  zero_end  = p;
    int*   offsets   = (int*)carve((size_t)Nd * 4);
    int*   blockSums = (int*)carve((size_t)nb * 4);
    int*   perm_src  = (int*)carve((size_t)E * 4);
    uint2* ofl       = (uint2*)carve((size_t)OFL_CAP * 8);

    size_t used = (size_t)(p - (char*)d_ws);
    size_t bins_bytes = (size_t)NB * BUCKET_CAP * 8;
    int use_bins = (NB <= MAXB && used + bins_bytes + 256 <= ws_size) ? 1 : 0;
    uint2* bins = use_bins ? (uint2*)carve(bins_bytes) : nullptr;

    used = (size_t)(p - (char*)d_ws);
    size_t bf_bytes = (size_t)Ns * D * 2;
    int use_bf16 = (used + bf_bytes + 256 <= ws_size) ? 1 : 0;
    unsigned short* feat_bf = use_bf16 ? (unsigned short*)carve(bf_bytes) : nullptr;

    hipMemsetAsync(counts, 0, (size_t)(zero_end - (char*)counts), stream);

    int total = Ns + Nd;
    prep_kernel<<<(total + 3) / 4, 256, 0, stream>>>(feat_src, feat_dst, attn_l, attn_r,
                                                     el, er, feat_bf, use_bf16, Ns, Nd);
    if (use_bins) {
        int chunk = (E + PART_WGS - 1) / PART_WGS;
        partition_kernel<<<PART_WGS, 256, 0, stream>>>(src, dst, E, chunk, NB, counts,
                                                       bins, bcur, ofl, ofl_cnt);
    } else {
        hist_kernel<<<2048, 256, 0, stream>>>(dst, E, counts);
    }
    scan1_kernel<<<nb, 256, 0, stream>>>(counts, offsets, blockSums, Nd);
    scan2_kernel<<<1, 256, 0, stream>>>(blockSums, nb);
    scan3_kernel<<<nb, 256, 0, stream>>>(offsets, blockSums, Nd);
    if (use_bins) {
        drain_kernel<<<32, 256, 0, stream>>>(ofl, ofl_cnt, offsets, gcursor, perm_src);
        scatter_kernel<<<NB, 256, 0, stream>>>(bins, bcur, offsets, gcursor, perm_src, Nd);
    } else {
        fill_kernel<<<2048, 256, 0, stream>>>(src, dst, E, offsets, gcursor, perm_src);
    }
    if (use_bf16) {
        gat_aggregate_bf16_kernel<<<Nd, AGG_THREADS, 0, stream>>>(feat_bf, el, er, offsets,
                                                                  counts, perm_src, out, Nd);
    } else {
        gat_aggregate_f32_kernel<<<Nd, AGG_THREADS, 0, stream>>>(feat_src, el, er, offsets,
                                                                 counts, perm_src, out, Nd);
    }
}

// Round 5
// 318.592 us; speedup vs baseline: 2.8198x; 1.1568x over previous
//
#include <hip/hip_runtime.h>
#include <hip/hip_bf16.h>
#include <math.h>

#define D 128
#define AGG_THREADS 128
#define CHUNK 512
#define BSHIFT 8                 // 256 dst nodes per bucket
#define BUCKET_CAP 5120          // mean load 4096, sigma ~64 -> 16 sigma margin
#define OFL_CAP 8192
#define MAXB 1024                // max buckets supported by partition_kernel LDS
#define PART_WGS 256             // workgroups in partition pass

// ---------- helpers ----------
__device__ __forceinline__ unsigned short f2bf(float f) {
    union { float f; unsigned int u; } c; c.f = f;
    unsigned int u = c.u;
    unsigned int r = (u + 0x7FFFu + ((u >> 16) & 1u)) >> 16;  // RNE
    return (unsigned short)r;
}
__device__ __forceinline__ void unpack2(unsigned int w, float& lo, float& hi) {
    union { unsigned int u; float f; } c;
    c.u = w << 16;          lo = c.f;
    c.u = w & 0xFFFF0000u;  hi = c.f;
}

// ---------- prep: el/er dots + bf16 copy of feat_src ----------
__global__ void prep_kernel(const float* __restrict__ feat_src,
                            const float* __restrict__ feat_dst,
                            const float* __restrict__ attn_l,
                            const float* __restrict__ attn_r,
                            float* __restrict__ el, float* __restrict__ er,
                            unsigned short* __restrict__ feat_bf, int store_bf,
                            int Ns, int Nd) {
    int wave = threadIdx.x >> 6;
    int lane = threadIdx.x & 63;
    int node = blockIdx.x * 4 + wave;
    if (node >= Ns + Nd) return;
    bool is_src = node < Ns;
    const float* feat = is_src ? feat_src + (size_t)node * D
                               : feat_dst + (size_t)(node - Ns) * D;
    const float* attn = is_src ? attn_l : attn_r;
    float2 a = ((const float2*)attn)[lane];
    float2 v = ((const float2*)feat)[lane];
    if (is_src && store_bf) {
        ushort2 h; h.x = f2bf(v.x); h.y = f2bf(v.y);
        ((ushort2*)(feat_bf + (size_t)node * D))[lane] = h;
    }
    float s = v.x * a.x + v.y * a.y;
    #pragma unroll
    for (int off = 32; off > 0; off >>= 1)
        s += __shfl_down(s, off, 64);
    if (lane == 0) {
        if (is_src) el[node] = s;
        else        er[node - Ns] = s;
    }
}

// ---------- pass A: per-WG counting-sort partition into dst-range buckets ----------
// NO per-dst global atomics (that was ~140 us of stall). LDS bucket histogram ->
// one reservation atomic per (WG,bucket) -> LDS-ranked write into a private run.
__global__ void partition_kernel(const int* __restrict__ src, const int* __restrict__ dst,
                                 int E, int chunk, int nbk,
                                 uint2* __restrict__ bins, int* __restrict__ bcur,
                                 uint2* __restrict__ ofl, int* __restrict__ ofl_cnt) {
    __shared__ int hist[MAXB];
    __shared__ int lbase[MAXB];
    int tid = threadIdx.x;
    int e0 = blockIdx.x * chunk;
    int e1 = min(E, e0 + chunk);
    if (e0 >= E) return;

    for (int i = tid; i < nbk; i += 256) hist[i] = 0;
    __syncthreads();

    for (int k = e0 + tid; k < e1; k += 256)
        atomicAdd(&hist[dst[k] >> BSHIFT], 1);
    __syncthreads();

    for (int i = tid; i < nbk; i += 256) {
        int h = hist[i];
        lbase[i] = h ? atomicAdd(&bcur[i], h) : 0;
        hist[i] = 0;                       // reuse as local cursor
    }
    __syncthreads();

    for (int k = e0 + tid; k < e1; k += 256) {
        int s = src[k], j = dst[k];
        int b = j >> BSHIFT;
        int r = lbase[b] + atomicAdd(&hist[b], 1);
        if (r < BUCKET_CAP) {
            bins[(size_t)b * BUCKET_CAP + r] = make_uint2((unsigned)s, (unsigned)j);
        } else {
            int o = atomicAdd(ofl_cnt, 1);
            if (o < OFL_CAP) ofl[o] = make_uint2((unsigned)s, (unsigned)j);
        }
    }
}

// ---------- overflow edges -> counts (normally zero iterations) ----------
__global__ void ofl_count_kernel(const uint2* __restrict__ ofl, const int* __restrict__ ofl_cnt,
                                 int* __restrict__ counts) {
    int n = min(*ofl_cnt, OFL_CAP);
    int stride = gridDim.x * blockDim.x;
    for (int k = blockIdx.x * blockDim.x + threadIdx.x; k < n; k += stride)
        atomicAdd(&counts[ofl[k].y], 1);
}

// ---------- fused per-dst count (from bins) + block-local exclusive scan ----------
// Block b == bucket b (256 dsts). counts[i] on entry holds overflow part (usually 0).
__global__ void scan1_fused_kernel(const uint2* __restrict__ bins, const int* __restrict__ bcur,
                                   int* __restrict__ counts, int* __restrict__ offsets,
                                   int* __restrict__ blockSums, int Nd) {
    __shared__ int cnt_sh[256];
    __shared__ int tile[256];
    int b = blockIdx.x;
    int base = b << BSHIFT;
    int tid = threadIdx.x;
    cnt_sh[tid] = 0;
    __syncthreads();
    int n = min(bcur[b], BUCKET_CAP);
    const uint2* mybin = bins + (size_t)b * BUCKET_CAP;
    for (int t = tid; t < n; t += 256)
        atomicAdd(&cnt_sh[(int)mybin[t].y - base], 1);
    __syncthreads();
    int i = base + tid;
    int v = (i < Nd) ? (cnt_sh[tid] + counts[i]) : 0;   // + overflow part
    tile[tid] = v;
    __syncthreads();
    for (int off = 1; off < 256; off <<= 1) {
        int t = (tid >= off) ? tile[tid - off] : 0;
        __syncthreads();
        tile[tid] += t;
        __syncthreads();
    }
    int incl = tile[tid];
    if (i < Nd) { counts[i] = v; offsets[i] = incl - v; }
    if (tid == 255) blockSums[b] = incl;
}

// ---------- fallback scan1 (counts already built by hist) ----------
__global__ void scan1_kernel(const int* __restrict__ counts, int* __restrict__ offsets,
                             int* __restrict__ blockSums, int N) {
    __shared__ int tile[256];
    int tid = threadIdx.x;
    int i = blockIdx.x * 256 + tid;
    int v = (i < N) ? counts[i] : 0;
    tile[tid] = v;
    __syncthreads();
    for (int off = 1; off < 256; off <<= 1) {
        int t = (tid >= off) ? tile[tid - off] : 0;
        __syncthreads();
        tile[tid] += t;
        __syncthreads();
    }
    int incl = tile[tid];
    if (i < N) offsets[i] = incl - v;          // block-local exclusive
    if (tid == 255) blockSums[blockIdx.x] = incl;
}

__global__ void scan2_kernel(int* __restrict__ bs, int nb) {
    __shared__ int tile[256];
    int tid = threadIdx.x;
    int carry = 0;
    for (int base = 0; base < nb; base += 256) {
        int i = base + tid;
        int v = (i < nb) ? bs[i] : 0;
        __syncthreads();
        tile[tid] = v;
        __syncthreads();
        for (int off = 1; off < 256; off <<= 1) {
            int t = (tid >= off) ? tile[tid - off] : 0;
            __syncthreads();
            tile[tid] += t;
            __syncthreads();
        }
        int incl = tile[tid];
        if (i < nb) bs[i] = incl - v + carry;   // global exclusive
        carry += tile[255];
    }
}

// ---------- drain overflow edges into perm (normally zero work) ----------
__global__ void drain_kernel(const uint2* __restrict__ ofl, const int* __restrict__ ofl_cnt,
                             const int* __restrict__ offsets, const int* __restrict__ bsum,
                             int* __restrict__ gcursor, int* __restrict__ perm_src) {
    int n = min(*ofl_cnt, OFL_CAP);
    int stride = gridDim.x * blockDim.x;
    for (int k = blockIdx.x * blockDim.x + threadIdx.x; k < n; k += stride) {
        uint2 e = ofl[k];
        int j = (int)e.y;
        int p = offsets[j] + bsum[j >> BSHIFT] + atomicAdd(&gcursor[j], 1);
        perm_src[p] = (int)e.x;
    }
}

// ---------- pass B: per-bucket LDS-ranked scatter into CSR ----------
__global__ void scatter_kernel(const uint2* __restrict__ bins, const int* __restrict__ bcur,
                               const int* __restrict__ offsets, const int* __restrict__ bsum,
                               const int* __restrict__ gcursor,
                               int* __restrict__ perm_src, int Nd) {
    __shared__ int lcur[1 << BSHIFT];
    int b = blockIdx.x;
    int base = b << BSHIFT;
    int tid = threadIdx.x;
    if (base + tid < Nd) lcur[tid] = gcursor[base + tid];  // start after overflow ranks
    __syncthreads();
    int bs = bsum[b];
    int n = min(bcur[b], BUCKET_CAP);
    const uint2* mybin = bins + (size_t)b * BUCKET_CAP;
    for (int t = tid; t < n; t += 256) {
        uint2 e = mybin[t];
        int j = (int)e.y;
        int rank = atomicAdd(&lcur[j - base], 1);
        perm_src[offsets[j] + bs + rank] = (int)e.x;
    }
}

// ---------- fallback: histogram + atomic fill ----------
__global__ void hist_kernel(const int* __restrict__ dst, int E, int* __restrict__ counts) {
    int stride = gridDim.x * blockDim.x;
    for (int k = blockIdx.x * blockDim.x + threadIdx.x; k < E; k += stride)
        atomicAdd(&counts[dst[k]], 1);
}
__global__ void fill_kernel(const int* __restrict__ src, const int* __restrict__ dst, int E,
                            const int* __restrict__ offsets, const int* __restrict__ bsum,
                            int* __restrict__ cursor, int* __restrict__ perm_src) {
    int stride = gridDim.x * blockDim.x;
    for (int k = blockIdx.x * blockDim.x + threadIdx.x; k < E; k += stride) {
        int j = dst[k];
        int p = offsets[j] + bsum[j >> BSHIFT] + atomicAdd(&cursor[j], 1);
        perm_src[p] = src[k];
    }
}

// ---------- block reductions (128 threads = 2 waves) ----------
__device__ __forceinline__ float block_max128(float v, float* red, int tid) {
    #pragma unroll
    for (int off = 32; off > 0; off >>= 1)
        v = fmaxf(v, __shfl_down(v, off, 64));
    __syncthreads();
    if ((tid & 63) == 0) red[tid >> 6] = v;
    __syncthreads();
    return fmaxf(red[0], red[1]);
}
__device__ __forceinline__ float block_sum128(float v, float* red, int tid) {
    #pragma unroll
    for (int off = 32; off > 0; off >>= 1)
        v += __shfl_down(v, off, 64);
    __syncthreads();
    if ((tid & 63) == 0) red[tid >> 6] = v;
    __syncthreads();
    return red[0] + red[1];
}

// ---------- bf16-vectorized aggregate ----------
__global__ void gat_aggregate_bf16_kernel(const unsigned short* __restrict__ feat_bf,
                                          const float* __restrict__ el,
                                          const float* __restrict__ er,
                                          const int* __restrict__ offsets,
                                          const int* __restrict__ bsum,
                                          const int* __restrict__ counts,
                                          const int* __restrict__ perm_src,
                                          float* __restrict__ out, int Nd) {
    __shared__ float w_sh[CHUNK];
    __shared__ int   s_sh[CHUNK];
    __shared__ float red[2];
    __shared__ float acc_sh[8][D];

    int j = blockIdx.x;
    int tid = threadIdx.x;
    int cnt = counts[j];
    size_t orow = (size_t)j * D;
    if (cnt == 0) { out[orow + tid] = 0.0f; return; }

    int beg = offsets[j] + bsum[j >> BSHIFT];
    float erj = er[j];
    int g = tid >> 4, u = tid & 15;
    float acc[8];
    #pragma unroll
    for (int k = 0; k < 8; ++k) acc[k] = 0.0f;
    float inv;
    const unsigned short* fb = feat_bf + (size_t)u * 8;

    if (cnt <= CHUNK) {
        float lmax = -INFINITY;
        for (int t = tid; t < cnt; t += AGG_THREADS) {
            int s = perm_src[beg + t];
            float e = el[s] + erj;
            e = (e >= 0.0f) ? e : 0.01f * e;  // leaky_relu
            s_sh[t] = s;
            w_sh[t] = e;
            lmax = fmaxf(lmax, e);
        }
        float m = block_max128(lmax, red, tid);
        float lsum = 0.0f;
        for (int t = tid; t < cnt; t += AGG_THREADS) {
            float a = __expf(w_sh[t] - m);
            w_sh[t] = a;
            lsum += a;
        }
        float den = block_sum128(lsum, red, tid);
        inv = 1.0f / den;
        __syncthreads();
        for (int t = g; t < cnt; t += 8) {
            int s = s_sh[t];
            float w = w_sh[t];
            uint4 v = *(const uint4*)(fb + (size_t)s * D);
            float f[8];
            unpack2(v.x, f[0], f[1]); unpack2(v.y, f[2], f[3]);
            unpack2(v.z, f[4], f[5]); unpack2(v.w, f[6], f[7]);
            #pragma unroll
            for (int k = 0; k < 8; ++k) acc[k] += w * f[k];
        }
    } else {
        float lmax = -INFINITY;
        for (int t = tid; t < cnt; t += AGG_THREADS) {
            int s = perm_src[beg + t];
            float e = el[s] + erj;
            e = (e >= 0.0f) ? e : 0.01f * e;
            lmax = fmaxf(lmax, e);
        }
        float m = block_max128(lmax, red, tid);
        float lsum = 0.0f;
        for (int t = tid; t < cnt; t += AGG_THREADS) {
            int s = perm_src[beg + t];
            float e = el[s] + erj;
            e = (e >= 0.0f) ? e : 0.01f * e;
            lsum += __expf(e - m);
        }
        float den = block_sum128(lsum, red, tid);
        inv = 1.0f / den;
        for (int base = 0; base < cnt; base += CHUNK) {
            int n = min(CHUNK, cnt - base);
            __syncthreads();
            for (int t = tid; t < n; t += AGG_THREADS) {
                int s = perm_src[beg + base + t];
                float e = el[s] + erj;
                e = (e >= 0.0f) ? e : 0.01f * e;
                s_sh[t] = s;
                w_sh[t] = __expf(e - m);
            }
            __syncthreads();
            for (int t = g; t < n; t += 8) {
                int s = s_sh[t];
                float w = w_sh[t];
                uint4 v = *(const uint4*)(fb + (size_t)s * D);
                float f[8];
                unpack2(v.x, f[0], f[1]); unpack2(v.y, f[2], f[3]);
                unpack2(v.z, f[4], f[5]); unpack2(v.w, f[6], f[7]);
                #pragma unroll
                for (int k = 0; k < 8; ++k) acc[k] += w * f[k];
            }
        }
    }
    #pragma unroll
    for (int k = 0; k < 8; ++k) acc_sh[g][u * 8 + k] = acc[k];
    __syncthreads();
    float r = 0.0f;
    #pragma unroll
    for (int g2 = 0; g2 < 8; ++g2) r += acc_sh[g2][tid];
    out[orow + tid] = r * inv;
}

// ---------- fp32 fallback aggregate ----------
__global__ void gat_aggregate_f32_kernel(const float* __restrict__ feat_src,
                                         const float* __restrict__ el,
                                         const float* __restrict__ er,
                                         const int* __restrict__ offsets,
                                         const int* __restrict__ bsum,
                                         const int* __restrict__ counts,
                                         const int* __restrict__ perm_src,
                                         float* __restrict__ out, int Nd) {
    __shared__ float w_sh[CHUNK];
    __shared__ int   s_sh[CHUNK];
    __shared__ float red[2];

    int j = blockIdx.x;
    int tid = threadIdx.x;
    int cnt = counts[j];
    size_t orow = (size_t)j * D;
    if (cnt == 0) { out[orow + tid] = 0.0f; return; }

    int beg = offsets[j] + bsum[j >> BSHIFT];
    float erj = er[j];
    float acc = 0.0f;
    float inv;

    if (cnt <= CHUNK) {
        float lmax = -INFINITY;
        for (int t = tid; t < cnt; t += AGG_THREADS) {
            int s = perm_src[beg + t];
            float e = el[s] + erj;
            e = (e >= 0.0f) ? e : 0.01f * e;
            s_sh[t] = s;
            w_sh[t] = e;
            lmax = fmaxf(lmax, e);
        }
        float m = block_max128(lmax, red, tid);
        float lsum = 0.0f;
        for (int t = tid; t < cnt; t += AGG_THREADS) {
            float a = __expf(w_sh[t] - m);
            w_sh[t] = a;
            lsum += a;
        }
        float den = block_sum128(lsum, red, tid);
        inv = 1.0f / den;
        __syncthreads();
        int t = 0;
        for (; t + 4 <= cnt; t += 4) {
            float f0 = feat_src[(size_t)s_sh[t + 0] * D + tid];
            float f1 = feat_src[(size_t)s_sh[t + 1] * D + tid];
            float f2 = feat_src[(size_t)s_sh[t + 2] * D + tid];
            float f3 = feat_src[(size_t)s_sh[t + 3] * D + tid];
            acc += f0 * w_sh[t + 0] + f1 * w_sh[t + 1] + f2 * w_sh[t + 2] + f3 * w_sh[t + 3];
        }
        for (; t < cnt; ++t)
            acc += feat_src[(size_t)s_sh[t] * D + tid] * w_sh[t];
    } else {
        float lmax = -INFINITY;
        for (int t = tid; t < cnt; t += AGG_THREADS) {
            int s = perm_src[beg + t];
            float e = el[s] + erj;
            e = (e >= 0.0f) ? e : 0.01f * e;
            lmax = fmaxf(lmax, e);
        }
        float m = block_max128(lmax, red, tid);
        float lsum = 0.0f;
        for (int t = tid; t < cnt; t += AGG_THREADS) {
            int s = perm_src[beg + t];
            float e = el[s] + erj;
            e = (e >= 0.0f) ? e : 0.01f * e;
            lsum += __expf(e - m);
        }
        float den = block_sum128(lsum, red, tid);
        inv = 1.0f / den;
        for (int base = 0; base < cnt; base += CHUNK) {
            int n = min(CHUNK, cnt - base);
            __syncthreads();
            for (int t = tid; t < n; t += AGG_THREADS) {
                int s = perm_src[beg + base + t];
                float e = el[s] + erj;
                e = (e >= 0.0f) ? e : 0.01f * e;
                s_sh[t] = s;
                w_sh[t] = __expf(e - m);
            }
            __syncthreads();
            for (int t = 0; t < n; ++t)
                acc += feat_src[(size_t)s_sh[t] * D + tid] * w_sh[t];
        }
    }
    out[orow + tid] = acc * inv;
}

extern "C" void kernel_launch(void* const* d_in, const int* in_sizes, int n_in,
                              void* d_out, int out_size, void* d_ws, size_t ws_size,
                              hipStream_t stream) {
    const float* feat_src = (const float*)d_in[0];
    const float* feat_dst = (const float*)d_in[1];
    const int*   src      = (const int*)d_in[2];
    const int*   dst      = (const int*)d_in[3];
    const float* attn_l   = (const float*)d_in[4];
    const float* attn_r   = (const float*)d_in[5];
    float* out = (float*)d_out;

    int Ns = in_sizes[0] / D;
    int Nd = in_sizes[1] / D;
    int E  = in_sizes[2];
    int NB = (Nd + (1 << BSHIFT) - 1) >> BSHIFT;   // buckets == scan blocks

    // workspace carve (256B aligned); zero-init region is contiguous: counts..ofl_cnt
    char* p = (char*)d_ws;
    auto carve = [&](size_t bytes) { void* r = (void*)p; p += (bytes + 255) & ~(size_t)255; return r; };
    float* el        = (float*)carve((size_t)Ns * 4);
    float* er        = (float*)carve((size_t)Nd * 4);
    int*   counts    = (int*)carve((size_t)Nd * 4);
    int*   gcursor   = (int*)carve((size_t)Nd * 4);
    int*   bcur      = (int*)carve((size_t)NB * 4);
    int*   ofl_cnt   = (int*)carve(4);
    char*  zero_end  = p;
    int*   offsets   = (int*)carve((size_t)Nd * 4);
    int*   blockSums = (int*)carve((size_t)NB * 4);
    int*   perm_src  = (int*)carve((size_t)E * 4);
    uint2* ofl       = (uint2*)carve((size_t)OFL_CAP * 8);

    size_t used = (size_t)(p - (char*)d_ws);
    size_t bins_bytes = (size_t)NB * BUCKET_CAP * 8;
    int use_bins = (NB <= MAXB && used + bins_bytes + 256 <= ws_size) ? 1 : 0;
    uint2* bins = use_bins ? (uint2*)carve(bins_bytes) : nullptr;

    used = (size_t)(p - (char*)d_ws);
    size_t bf_bytes = (size_t)Ns * D * 2;
    int use_bf16 = (used + bf_bytes + 256 <= ws_size) ? 1 : 0;
    unsigned short* feat_bf = use_bf16 ? (unsigned short*)carve(bf_bytes) : nullptr;

    hipMemsetAsync(counts, 0, (size_t)(zero_end - (char*)counts), stream);

    int total = Ns + Nd;
    prep_kernel<<<(total + 3) / 4, 256, 0, stream>>>(feat_src, feat_dst, attn_l, attn_r,
                                                     el, er, feat_bf, use_bf16, Ns, Nd);
    if (use_bins) {
        int chunk = (E + PART_WGS - 1) / PART_WGS;
        partition_kernel<<<PART_WGS, 256, 0, stream>>>(src, dst, E, chunk, NB,
                                                       bins, bcur, ofl, ofl_cnt);
        ofl_count_kernel<<<32, 256, 0, stream>>>(ofl, ofl_cnt, counts);
        scan1_fused_kernel<<<NB, 256, 0, stream>>>(bins, bcur, counts, offsets, blockSums, Nd);
        scan2_kernel<<<1, 256, 0, stream>>>(blockSums, NB);
        drain_kernel<<<32, 256, 0, stream>>>(ofl, ofl_cnt, offsets, blockSums, gcursor, perm_src);
        scatter_kernel<<<NB, 256, 0, stream>>>(bins, bcur, offsets, blockSums, gcursor,
                                               perm_src, Nd);
    } else {
        hist_kernel<<<2048, 256, 0, stream>>>(dst, E, counts);
        scan1_kernel<<<NB, 256, 0, stream>>>(counts, offsets, blockSums, Nd);
        scan2_kernel<<<1, 256, 0, stream>>>(blockSums, NB);
        fill_kernel<<<2048, 256, 0, stream>>>(src, dst, E, offsets, blockSums, gcursor, perm_src);
    }
    if (use_bf16) {
        gat_aggregate_bf16_kernel<<<Nd, AGG_THREADS, 0, stream>>>(feat_bf, el, er, offsets,
                                                                  blockSums, counts, perm_src,
                                                                  out, Nd);
    } else {
        gat_aggregate_f32_kernel<<<Nd, AGG_THREADS, 0, stream>>>(feat_src, el, er, offsets,
                                                                 blockSums, counts, perm_src,
                                                                 out, Nd);
    }
}

// Round 6
// 276.459 us; speedup vs baseline: 3.2495x; 1.1524x over previous
//
#include <hip/hip_runtime.h>
#include <hip/hip_bf16.h>
#include <math.h>

#define D 128
#define AGG_THREADS 128
#define CHUNK 512
#define BSHIFT 8                 // 256 dst nodes per bucket
#define MAXB 1024                // max buckets (LDS arrays in partition)
#define MAXWG 1024               // max partition WGs (LDS arrays in bucket kernel)
#define PCHUNK 4096              // edges per partition WG
#define PE 16                    // PCHUNK / 256
#define EBUF_CAP 5120            // LDS staging cap in bucket kernel (mean 4096, 16 sigma)
#define PR 8192                  // perm region stride per bucket (45 sigma)

// ---------- helpers ----------
__device__ __forceinline__ unsigned short f2bf(float f) {
    union { float f; unsigned int u; } c; c.f = f;
    unsigned int u = c.u;
    unsigned int r = (u + 0x7FFFu + ((u >> 16) & 1u)) >> 16;  // RNE
    return (unsigned short)r;
}
__device__ __forceinline__ void unpack2(unsigned int w, float& lo, float& hi) {
    union { unsigned int u; float f; } c;
    c.u = w << 16;          lo = c.f;
    c.u = w & 0xFFFF0000u;  hi = c.f;
}

// ---------- prep: el/er dots + bf16 copy of feat_src; 2 rows per wave, float4 ----------
__global__ void prep_kernel(const float* __restrict__ feat_src,
                            const float* __restrict__ feat_dst,
                            const float* __restrict__ attn_l,
                            const float* __restrict__ attn_r,
                            float* __restrict__ el, float* __restrict__ er,
                            unsigned short* __restrict__ feat_bf, int store_bf,
                            int Ns, int Nd) {
    int half = threadIdx.x >> 5;           // 0..7 (8 rows per 256-thread block)
    int lane = threadIdx.x & 31;
    int node = blockIdx.x * 8 + half;
    if (node >= Ns + Nd) return;
    bool is_src = node < Ns;
    const float* feat = is_src ? feat_src + (size_t)node * D
                               : feat_dst + (size_t)(node - Ns) * D;
    const float* attn = is_src ? attn_l : attn_r;
    float4 a = ((const float4*)attn)[lane];
    float4 v = ((const float4*)feat)[lane];
    if (is_src && store_bf) {
        ushort4 h; h.x = f2bf(v.x); h.y = f2bf(v.y); h.z = f2bf(v.z); h.w = f2bf(v.w);
        ((ushort4*)(feat_bf + (size_t)node * D))[lane] = h;
    }
    float s = v.x * a.x + v.y * a.y + v.z * a.z + v.w * a.w;
    #pragma unroll
    for (int off = 16; off > 0; off >>= 1)
        s += __shfl_xor(s, off, 64);       // xor<=16 stays within each 32-lane half
    if (lane == 0) {
        if (is_src) el[node] = s;
        else        er[node - Ns] = s;
    }
}

// ---------- partition: WG-local counting sort by bucket, ZERO global atomics ----------
// WG w: load 4096 edges into regs, LDS bucket histogram, wave-0 scan, LDS-ranked
// placement into a sorted LDS buffer, linear coalesced write to bins + tables.
__global__ void partition_kernel(const int* __restrict__ src, const int* __restrict__ dst,
                                 int E, int nbk,
                                 uint2* __restrict__ bins,
                                 int* __restrict__ cnt_tab, int* __restrict__ loc_tab) {
    __shared__ int hist[MAXB];
    __shared__ int lstart[MAXB];
    __shared__ int cursor[MAXB];
    __shared__ uint2 sbuf[PCHUNK];         // 32 KB
    int w = blockIdx.x, tid = threadIdx.x;
    int e0 = w * PCHUNK;
    int e1 = min(E, e0 + PCHUNK);
    int n = e1 - e0;

    for (int i = tid; i < nbk; i += 256) hist[i] = 0;
    __syncthreads();

    int es[PE], ed[PE];
    #pragma unroll
    for (int k = 0; k < PE; ++k) {
        int idx = e0 + k * 256 + tid;
        if (idx < e1) {
            es[k] = src[idx];
            ed[k] = dst[idx];
            atomicAdd(&hist[ed[k] >> BSHIFT], 1);
        }
    }
    __syncthreads();

    // exclusive scan of hist[0..nbk) by wave 0, 64-wide chunks
    if (tid < 64) {
        int carry = 0;
        for (int c = 0; c < nbk; c += 64) {
            int i = c + tid;
            int v = (i < nbk) ? hist[i] : 0;
            int x = v;
            #pragma unroll
            for (int off = 1; off < 64; off <<= 1) {
                int t = __shfl_up(x, off, 64);
                if (tid >= off) x += t;
            }
            if (i < nbk) lstart[i] = x - v + carry;
            carry += __shfl(x, 63, 64);
        }
    }
    __syncthreads();

    for (int i = tid; i < nbk; i += 256) {
        cnt_tab[(size_t)w * nbk + i] = hist[i];
        loc_tab[(size_t)w * nbk + i] = lstart[i];
        cursor[i] = 0;
    }
    __syncthreads();

    #pragma unroll
    for (int k = 0; k < PE; ++k) {
        int idx = e0 + k * 256 + tid;
        if (idx < e1) {
            int b = ed[k] >> BSHIFT;
            int r = lstart[b] + atomicAdd(&cursor[b], 1);
            sbuf[r] = make_uint2((unsigned)es[k], (unsigned)ed[k]);
        }
    }
    __syncthreads();

    uint2* obase = bins + (size_t)w * PCHUNK;
    for (int t = tid; t < n; t += 256) obase[t] = sbuf[t];   // coalesced
}

// ---------- bucket kernel: gather segments -> count -> scan -> rank -> perm ----------
// One 256-thread block per bucket. Fixed perm region of PR entries per bucket.
__global__ void bucket_kernel(const uint2* __restrict__ bins,
                              const int* __restrict__ cnt_tab, const int* __restrict__ loc_tab,
                              int nbk, int nwg,
                              int* __restrict__ counts, int* __restrict__ offs,
                              int* __restrict__ perm, int Nd) {
    __shared__ uint2 ebuf[EBUF_CAP];       // 40 KB
    __shared__ int wcnt[MAXWG];
    __shared__ int wdst[MAXWG];
    __shared__ int cnt256[256];
    __shared__ int off256[256];
    __shared__ int cur256[256];
    __shared__ int tile[256];
    __shared__ int total_sh;

    int b = blockIdx.x, tid = threadIdx.x;
    int base = b << BSHIFT;

    for (int i = tid; i < nwg; i += 256) wcnt[i] = cnt_tab[(size_t)i * nbk + b];
    __syncthreads();
    if (tid < 64) {                        // exclusive scan over nwg segment counts
        int carry = 0;
        for (int c = 0; c < nwg; c += 64) {
            int i = c + tid;
            int v = (i < nwg) ? wcnt[i] : 0;
            int x = v;
            #pragma unroll
            for (int off = 1; off < 64; off <<= 1) {
                int t = __shfl_up(x, off, 64);
                if (tid >= off) x += t;
            }
            if (i < nwg) wdst[i] = x - v + carry;
            carry += __shfl(x, 63, 64);
        }
        if (tid == 0) total_sh = carry;
    }
    cnt256[tid] = 0;
    cur256[tid] = 0;
    __syncthreads();
    int n = total_sh;
    bool fits = (n <= EBUF_CAP);

    if (fits) {
        // stage all segments into LDS (thread t handles WGs t, t+256, ...)
        for (int w = tid; w < nwg; w += 256) {
            int c = wcnt[w];
            if (c) {
                const uint2* sp = bins + (size_t)w * PCHUNK + loc_tab[(size_t)w * nbk + b];
                int d0 = wdst[w];
                for (int k = 0; k < c; ++k) ebuf[d0 + k] = sp[k];
            }
        }
        __syncthreads();
        for (int t = tid; t < n; t += 256)
            atomicAdd(&cnt256[(int)ebuf[t].y - base], 1);
    } else {
        // slow path (statistically unreachable): count straight from global
        for (int w = tid; w < nwg; w += 256) {
            int c = wcnt[w];
            const uint2* sp = bins + (size_t)w * PCHUNK + loc_tab[(size_t)w * nbk + b];
            for (int k = 0; k < c; ++k)
                atomicAdd(&cnt256[(int)sp[k].y - base], 1);
        }
        __syncthreads();
    }
    __syncthreads();

    // 256-wide exclusive scan of per-dst counts
    int v = cnt256[tid];
    tile[tid] = v;
    __syncthreads();
    for (int off = 1; off < 256; off <<= 1) {
        int t = (tid >= off) ? tile[tid - off] : 0;
        __syncthreads();
        tile[tid] += t;
        __syncthreads();
    }
    int myoff = tile[tid] - v;
    off256[tid] = myoff;
    int i = base + tid;
    if (i < Nd) {
        int c = v;
        if (myoff + c > PR) c = max(0, PR - myoff);   // paranoia clamp (n > PR impossible)
        counts[i] = c;
        offs[i]   = myoff;
    }
    __syncthreads();

    // rank + write perm into this bucket's fixed region
    size_t rbase = (size_t)b * PR;
    if (fits) {
        for (int t = tid; t < n; t += 256) {
            uint2 e = ebuf[t];
            int d = (int)e.y - base;
            int r = atomicAdd(&cur256[d], 1);
            int slot = off256[d] + r;
            if (slot < PR) perm[rbase + slot] = (int)e.x;
        }
    } else {
        for (int w = tid; w < nwg; w += 256) {
            int c = wcnt[w];
            const uint2* sp = bins + (size_t)w * PCHUNK + loc_tab[(size_t)w * nbk + b];
            for (int k = 0; k < c; ++k) {
                uint2 e = sp[k];
                int d = (int)e.y - base;
                int r = atomicAdd(&cur256[d], 1);
                int slot = off256[d] + r;
                if (slot < PR) perm[rbase + slot] = (int)e.x;
            }
        }
    }
}

// ---------- block reductions (128 threads = 2 waves) ----------
__device__ __forceinline__ float block_max128(float v, float* red, int tid) {
    #pragma unroll
    for (int off = 32; off > 0; off >>= 1)
        v = fmaxf(v, __shfl_down(v, off, 64));
    __syncthreads();
    if ((tid & 63) == 0) red[tid >> 6] = v;
    __syncthreads();
    return fmaxf(red[0], red[1]);
}
__device__ __forceinline__ float block_sum128(float v, float* red, int tid) {
    #pragma unroll
    for (int off = 32; off > 0; off >>= 1)
        v += __shfl_down(v, off, 64);
    __syncthreads();
    if ((tid & 63) == 0) red[tid >> 6] = v;
    __syncthreads();
    return red[0] + red[1];
}

// ---------- bf16-vectorized aggregate (bucket-region perm layout) ----------
__global__ void gat_aggregate_bf16_kernel(const unsigned short* __restrict__ feat_bf,
                                          const float* __restrict__ el,
                                          const float* __restrict__ er,
                                          const int* __restrict__ offs,
                                          const int* __restrict__ counts,
                                          const int* __restrict__ perm,
                                          float* __restrict__ out, int Nd) {
    __shared__ float w_sh[CHUNK];
    __shared__ int   s_sh[CHUNK];
    __shared__ float red[2];
    __shared__ float acc_sh[8][D];

    int j = blockIdx.x;
    int tid = threadIdx.x;
    int cnt = counts[j];
    size_t orow = (size_t)j * D;
    if (cnt == 0) { out[orow + tid] = 0.0f; return; }

    size_t beg = (size_t)(j >> BSHIFT) * PR + offs[j];
    float erj = er[j];
    int g = tid >> 4, u = tid & 15;
    float acc[8];
    #pragma unroll
    for (int k = 0; k < 8; ++k) acc[k] = 0.0f;
    float inv;
    const unsigned short* fb = feat_bf + (size_t)u * 8;

    if (cnt <= CHUNK) {
        float lmax = -INFINITY;
        for (int t = tid; t < cnt; t += AGG_THREADS) {
            int s = perm[beg + t];
            float e = el[s] + erj;
            e = (e >= 0.0f) ? e : 0.01f * e;  // leaky_relu
            s_sh[t] = s;
            w_sh[t] = e;
            lmax = fmaxf(lmax, e);
        }
        float m = block_max128(lmax, red, tid);
        float lsum = 0.0f;
        for (int t = tid; t < cnt; t += AGG_THREADS) {
            float a = __expf(w_sh[t] - m);
            w_sh[t] = a;
            lsum += a;
        }
        float den = block_sum128(lsum, red, tid);
        inv = 1.0f / den;
        __syncthreads();
        for (int t = g; t < cnt; t += 8) {
            int s = s_sh[t];
            float w = w_sh[t];
            uint4 v = *(const uint4*)(fb + (size_t)s * D);
            float f[8];
            unpack2(v.x, f[0], f[1]); unpack2(v.y, f[2], f[3]);
            unpack2(v.z, f[4], f[5]); unpack2(v.w, f[6], f[7]);
            #pragma unroll
            for (int k = 0; k < 8; ++k) acc[k] += w * f[k];
        }
    } else {
        float lmax = -INFINITY;
        for (int t = tid; t < cnt; t += AGG_THREADS) {
            int s = perm[beg + t];
            float e = el[s] + erj;
            e = (e >= 0.0f) ? e : 0.01f * e;
            lmax = fmaxf(lmax, e);
        }
        float m = block_max128(lmax, red, tid);
        float lsum = 0.0f;
        for (int t = tid; t < cnt; t += AGG_THREADS) {
            int s = perm[beg + t];
            float e = el[s] + erj;
            e = (e >= 0.0f) ? e : 0.01f * e;
            lsum += __expf(e - m);
        }
        float den = block_sum128(lsum, red, tid);
        inv = 1.0f / den;
        for (int bb = 0; bb < cnt; bb += CHUNK) {
            int n = min(CHUNK, cnt - bb);
            __syncthreads();
            for (int t = tid; t < n; t += AGG_THREADS) {
                int s = perm[beg + bb + t];
                float e = el[s] + erj;
                e = (e >= 0.0f) ? e : 0.01f * e;
                s_sh[t] = s;
                w_sh[t] = __expf(e - m);
            }
            __syncthreads();
            for (int t = g; t < n; t += 8) {
                int s = s_sh[t];
                float w = w_sh[t];
                uint4 v = *(const uint4*)(fb + (size_t)s * D);
                float f[8];
                unpack2(v.x, f[0], f[1]); unpack2(v.y, f[2], f[3]);
                unpack2(v.z, f[4], f[5]); unpack2(v.w, f[6], f[7]);
                #pragma unroll
                for (int k = 0; k < 8; ++k) acc[k] += w * f[k];
            }
        }
    }
    #pragma unroll
    for (int k = 0; k < 8; ++k) acc_sh[g][u * 8 + k] = acc[k];
    __syncthreads();
    float r = 0.0f;
    #pragma unroll
    for (int g2 = 0; g2 < 8; ++g2) r += acc_sh[g2][tid];
    out[orow + tid] = r * inv;
}

// ================= fallback pipeline (only if workspace too small) =================
__global__ void hist_kernel(const int* __restrict__ dst, int E, int* __restrict__ counts) {
    int stride = gridDim.x * blockDim.x;
    for (int k = blockIdx.x * blockDim.x + threadIdx.x; k < E; k += stride)
        atomicAdd(&counts[dst[k]], 1);
}
__global__ void scan1_kernel(const int* __restrict__ counts, int* __restrict__ offsets,
                             int* __restrict__ blockSums, int N) {
    __shared__ int tile[256];
    int tid = threadIdx.x;
    int i = blockIdx.x * 256 + tid;
    int v = (i < N) ? counts[i] : 0;
    tile[tid] = v;
    __syncthreads();
    for (int off = 1; off < 256; off <<= 1) {
        int t = (tid >= off) ? tile[tid - off] : 0;
        __syncthreads();
        tile[tid] += t;
        __syncthreads();
    }
    int incl = tile[tid];
    if (i < N) offsets[i] = incl - v;
    if (tid == 255) blockSums[blockIdx.x] = incl;
}
__global__ void scan2_kernel(int* __restrict__ bs, int nb) {
    __shared__ int tile[256];
    int tid = threadIdx.x;
    int carry = 0;
    for (int base = 0; base < nb; base += 256) {
        int i = base + tid;
        int v = (i < nb) ? bs[i] : 0;
        __syncthreads();
        tile[tid] = v;
        __syncthreads();
        for (int off = 1; off < 256; off <<= 1) {
            int t = (tid >= off) ? tile[tid - off] : 0;
            __syncthreads();
            tile[tid] += t;
            __syncthreads();
        }
        int incl = tile[tid];
        if (i < nb) bs[i] = incl - v + carry;
        carry += tile[255];
    }
}
__global__ void fill_kernel(const int* __restrict__ src, const int* __restrict__ dst, int E,
                            const int* __restrict__ offsets, const int* __restrict__ bsum,
                            int* __restrict__ cursor, int* __restrict__ perm_src) {
    int stride = gridDim.x * blockDim.x;
    for (int k = blockIdx.x * blockDim.x + threadIdx.x; k < E; k += stride) {
        int j = dst[k];
        int p = offsets[j] + bsum[j >> BSHIFT] + atomicAdd(&cursor[j], 1);
        perm_src[p] = src[k];
    }
}
__global__ void gat_aggregate_f32_kernel(const float* __restrict__ feat_src,
                                         const float* __restrict__ el,
                                         const float* __restrict__ er,
                                         const int* __restrict__ offsets,
                                         const int* __restrict__ bsum,
                                         const int* __restrict__ counts,
                                         const int* __restrict__ perm_src,
                                         float* __restrict__ out, int Nd) {
    __shared__ float w_sh[CHUNK];
    __shared__ int   s_sh[CHUNK];
    __shared__ float red[2];
    int j = blockIdx.x;
    int tid = threadIdx.x;
    int cnt = counts[j];
    size_t orow = (size_t)j * D;
    if (cnt == 0) { out[orow + tid] = 0.0f; return; }
    int beg = offsets[j] + bsum[j >> BSHIFT];
    float erj = er[j];
    float acc = 0.0f;
    float inv;
    if (cnt <= CHUNK) {
        float lmax = -INFINITY;
        for (int t = tid; t < cnt; t += AGG_THREADS) {
            int s = perm_src[beg + t];
            float e = el[s] + erj;
            e = (e >= 0.0f) ? e : 0.01f * e;
            s_sh[t] = s; w_sh[t] = e;
            lmax = fmaxf(lmax, e);
        }
        float m = block_max128(lmax, red, tid);
        float lsum = 0.0f;
        for (int t = tid; t < cnt; t += AGG_THREADS) {
            float a = __expf(w_sh[t] - m);
            w_sh[t] = a; lsum += a;
        }
        float den = block_sum128(lsum, red, tid);
        inv = 1.0f / den;
        __syncthreads();
        for (int t = 0; t < cnt; ++t)
            acc += feat_src[(size_t)s_sh[t] * D + tid] * w_sh[t];
    } else {
        float lmax = -INFINITY;
        for (int t = tid; t < cnt; t += AGG_THREADS) {
            int s = perm_src[beg + t];
            float e = el[s] + erj;
            e = (e >= 0.0f) ? e : 0.01f * e;
            lmax = fmaxf(lmax, e);
        }
        float m = block_max128(lmax, red, tid);
        float lsum = 0.0f;
        for (int t = tid; t < cnt; t += AGG_THREADS) {
            int s = perm_src[beg + t];
            float e = el[s] + erj;
            e = (e >= 0.0f) ? e : 0.01f * e;
            lsum += __expf(e - m);
        }
        float den = block_sum128(lsum, red, tid);
        inv = 1.0f / den;
        for (int bb = 0; bb < cnt; bb += CHUNK) {
            int n = min(CHUNK, cnt - bb);
            __syncthreads();
            for (int t = tid; t < n; t += AGG_THREADS) {
                int s = perm_src[beg + bb + t];
                float e = el[s] + erj;
                e = (e >= 0.0f) ? e : 0.01f * e;
                s_sh[t] = s;
                w_sh[t] = __expf(e - m);
            }
            __syncthreads();
            for (int t = 0; t < n; ++t)
                acc += feat_src[(size_t)s_sh[t] * D + tid] * w_sh[t];
        }
    }
    out[orow + tid] = acc * inv;
}

extern "C" void kernel_launch(void* const* d_in, const int* in_sizes, int n_in,
                              void* d_out, int out_size, void* d_ws, size_t ws_size,
                              hipStream_t stream) {
    const float* feat_src = (const float*)d_in[0];
    const float* feat_dst = (const float*)d_in[1];
    const int*   src      = (const int*)d_in[2];
    const int*   dst      = (const int*)d_in[3];
    const float* attn_l   = (const float*)d_in[4];
    const float* attn_r   = (const float*)d_in[5];
    float* out = (float*)d_out;

    int Ns = in_sizes[0] / D;
    int Nd = in_sizes[1] / D;
    int E  = in_sizes[2];
    int NBK = (Nd + (1 << BSHIFT) - 1) >> BSHIFT;
    int NWG = (E + PCHUNK - 1) / PCHUNK;

    char* p = (char*)d_ws;
    auto carve = [&](size_t bytes) { void* r = (void*)p; p += (bytes + 255) & ~(size_t)255; return r; };
    float* el      = (float*)carve((size_t)Ns * 4);
    float* er      = (float*)carve((size_t)Nd * 4);
    int*   counts  = (int*)carve((size_t)Nd * 4);
    int*   offs    = (int*)carve((size_t)Nd * 4);       // fallback: 'offsets'
    int*   gcursor = (int*)carve((size_t)Nd * 4);       // fallback only
    int*   bsums   = (int*)carve((size_t)NBK * 4);      // fallback only
    int*   cnt_tab = (int*)carve((size_t)NWG * NBK * 4);
    int*   loc_tab = (int*)carve((size_t)NWG * NBK * 4);
    int*   perm    = (int*)carve((size_t)NBK * PR * 4); // >= E*4, shared w/ fallback
    uint2* bins    = (uint2*)carve((size_t)NWG * PCHUNK * 8);
    size_t used    = (size_t)(p - (char*)d_ws);
    size_t bf_bytes = (size_t)Ns * D * 2;
    unsigned short* feat_bf = (unsigned short*)carve(bf_bytes);

    int fast = (NBK <= MAXB && NWG <= MAXWG &&
                used + bf_bytes + 256 <= ws_size) ? 1 : 0;

    int total = Ns + Nd;
    if (fast) {
        prep_kernel<<<(total + 7) / 8, 256, 0, stream>>>(feat_src, feat_dst, attn_l, attn_r,
                                                         el, er, feat_bf, 1, Ns, Nd);
        partition_kernel<<<NWG, 256, 0, stream>>>(src, dst, E, NBK, bins, cnt_tab, loc_tab);
        bucket_kernel<<<NBK, 256, 0, stream>>>(bins, cnt_tab, loc_tab, NBK, NWG,
                                               counts, offs, perm, Nd);
        gat_aggregate_bf16_kernel<<<Nd, AGG_THREADS, 0, stream>>>(feat_bf, el, er, offs,
                                                                  counts, perm, out, Nd);
    } else {
        hipMemsetAsync(counts, 0, (size_t)Nd * 4, stream);
        hipMemsetAsync(gcursor, 0, (size_t)Nd * 4, stream);
        prep_kernel<<<(total + 7) / 8, 256, 0, stream>>>(feat_src, feat_dst, attn_l, attn_r,
                                                         el, er, nullptr, 0, Ns, Nd);
        hist_kernel<<<2048, 256, 0, stream>>>(dst, E, counts);
        scan1_kernel<<<NBK, 256, 0, stream>>>(counts, offs, bsums, Nd);
        scan2_kernel<<<1, 256, 0, stream>>>(bsums, NBK);
        fill_kernel<<<2048, 256, 0, stream>>>(src, dst, E, offs, bsums, gcursor, perm);
        gat_aggregate_f32_kernel<<<Nd, AGG_THREADS, 0, stream>>>(feat_src, el, er, offs,
                                                                 bsums, counts, perm, out, Nd);
    }
}